// Round 6
// baseline (196.010 us; speedup 1.0000x reference)
//
#include <hip/hip_runtime.h>

#define N 8192
#define L 13
#define SEGS 8
#define NSP (N / SEGS / 32)  // 32 MFMA-group iterations per filter wave
#define PARTROWS 416         // = N*L/256 (mix grid); prep fills rows 0..31, zeros rest

typedef _Float16 f16x8 __attribute__((ext_vector_type(8)));
typedef _Float16 f16x2 __attribute__((ext_vector_type(2)));
typedef float f32x4 __attribute__((ext_vector_type(4)));
union F16x8U { f16x8 v; f16x2 h[4]; };

#define C1 (-0.72134752044448f)   // -0.5/ln2
#define C2 (1.44269504088896f)    // log2(e)
#define EBIAS 6.0f                // e' = exp2(C2*x - EBIAS); scale cancels in e'/D'

// a1pack [spair(256)][lane(64)][j(8)] f16 — A-frags (k-side quintuple/octuple).
// qpack  [kc(256)][lane=g*16+col][j(8)] f16 = e'[kc*32+phys(g,j)][col]; col13=1.0, col14/15=0.
//   phys(g,j) = j<4 ? 4g+j : 16+4g+(j-4)

__global__ __launch_bounds__(256) void prep_kernel(const float* __restrict__ points,
                                                   const float* __restrict__ logits,
                                                   float* __restrict__ crd,
                                                   float* __restrict__ snx,
                                                   float* __restrict__ snf,
                                                   float* __restrict__ part,
                                                   unsigned short* __restrict__ a1pack,
                                                   unsigned short* __restrict__ qpack) {
  int t = threadIdx.x;
  int p = blockIdx.x * 256 + t;
  float c6[6];
#pragma unroll
  for (int d = 0; d < 6; ++d) { c6[d] = points[p * 6 + d]; crd[d * N + p] = c6[d]; }
  float sx = c6[0] * c6[0] + c6[1] * c6[1] + c6[2] * c6[2];
  float sf = c6[3] * c6[3] + c6[4] * c6[4] + c6[5] * c6[5];
  snx[p] = sx; snf[p] = sf;

  int spair = p >> 5, w = p & 31, rm = w & 15;
  int laneS = (w < 16 ? 0 : 32) + rm;
  int laneB = (w < 16 ? 16 : 48) + rm;
  f16x8 vs = { (_Float16)c6[0], (_Float16)c6[1], (_Float16)c6[2],
               (_Float16)sx, (_Float16)1.0f, (_Float16)0.0f, (_Float16)0.0f, (_Float16)0.0f };
  f16x8 vb = { (_Float16)c6[0], (_Float16)c6[1], (_Float16)c6[2],
               (_Float16)c6[3], (_Float16)c6[4], (_Float16)c6[5],
               (_Float16)(sx + sf), (_Float16)1.0f };
  ((f16x8*)a1pack)[(size_t)spair * 64 + laneS] = vs;
  ((f16x8*)a1pack)[(size_t)spair * 64 + laneB] = vb;

  int kc = p >> 5, kk = p & 31;
  int g = (kk < 16) ? (kk >> 2) : ((kk - 16) >> 2);
  int j2 = (kk < 16) ? (kk & 3) : (4 + (kk & 3));
  size_t qb = ((size_t)kc * 64 + g * 16) * 8 + j2;
  qpack[qb + 13 * 8] = 0x3C00;  // f16 1.0 (norm column)
  qpack[qb + 14 * 8] = 0;
  qpack[qb + 15 * 8] = 0;

  // initial unnormalized-softmax pack + per-block label sums
  __shared__ float buf[13][256];
#pragma unroll
  for (int l = 0; l < L; ++l) {
    float e = __builtin_amdgcn_exp2f(logits[p * L + l] * C2 - EBIAS);
    _Float16 h = (_Float16)e;
    qpack[qb + (size_t)l * 8] = *(unsigned short*)&h;
    buf[l][t] = e;
  }
  __syncthreads();
  for (int s = 128; s >= 1; s >>= 1) {
    if (t < s) {
#pragma unroll
      for (int l = 0; l < L; ++l) buf[l][t] += buf[l][t + s];
    }
    __syncthreads();
  }
  if (t < L) part[blockIdx.x * 16 + t] = buf[t][0];
  if (t < 192) part[(32 + blockIdx.x * 12 + (t >> 4)) * 16 + (t & 15)] = 0.f;
}

__global__ void mprep_kernel(const float* __restrict__ Ws, const float* __restrict__ Wb,
                             const float* __restrict__ C, float* __restrict__ M1,
                             float* __restrict__ M2) {
  int i = threadIdx.x;
  if (i < L * L) {
    int r = i / L, c = i % L;
    float a = 0.f, b = 0.f;
    for (int j = 0; j < L; ++j) {
      a += C[r * L + j] * Ws[j * L + c];
      b += C[r * L + j] * Wb[j * L + c];
    }
    M1[i] = a; M2[i] = b;
  }
}

// hot kernel: 4 waves/block, each wave owns TWO 16-p tiles (32 p).
// One (A,bq) load pair per 32 k feeds 12 MFMAs + 32 exps (2x arithmetic intensity).
__global__ __launch_bounds__(256) void filter_kernel(const float* __restrict__ crd,
                                                     const float* __restrict__ snx,
                                                     const float* __restrict__ snf,
                                                     const unsigned short* __restrict__ a1pack,
                                                     const unsigned short* __restrict__ qpack,
                                                     float* __restrict__ ps,
                                                     float* __restrict__ pb) {
  int tid = threadIdx.x;
  int lane = tid & 63, wave = tid >> 6;
  int g = lane >> 4, rm = lane & 15;
  int ptile = blockIdx.x * 128 + wave * 32;
  int seg = blockIdx.y;

  f16x8 z8 = {0, 0, 0, 0, 0, 0, 0, 0};
  f16x8 Bs0_0, Bb0_0, Bs1_0, Bb1_0;
  f16x8 Bs0_1, Bb0_1, Bs1_1, Bb1_1;

#define MAKE_B(SFX, P)                                                          \
  {                                                                             \
    float x0 = crd[P], x1 = crd[N + (P)], x2 = crd[2 * N + (P)];                \
    float f0 = crd[3 * N + (P)], f1 = crd[4 * N + (P)], f2 = crd[5 * N + (P)];  \
    float sx = snx[P], sf = snf[P];                                             \
    f16x8 spat = { (_Float16)(C2 * x0), (_Float16)(C2 * x1), (_Float16)(C2 * x2), \
                   (_Float16)C1, (_Float16)(C1 * sx),                           \
                   (_Float16)0.0f, (_Float16)0.0f, (_Float16)0.0f };            \
    f16x8 bil  = { (_Float16)(C2 * x0), (_Float16)(C2 * x1), (_Float16)(C2 * x2), \
                   (_Float16)(C2 * f0), (_Float16)(C2 * f1), (_Float16)(C2 * f2), \
                   (_Float16)C1, (_Float16)(C1 * (sx + sf)) };                  \
    Bs0_##SFX = (g == 0) ? spat : z8;                                           \
    Bb0_##SFX = (g == 1) ? bil : z8;                                            \
    Bs1_##SFX = (g == 2) ? spat : z8;                                           \
    Bb1_##SFX = (g == 3) ? bil : z8;                                            \
  }

  MAKE_B(0, ptile + rm)
  MAKE_B(1, ptile + 16 + rm)

  f32x4 acc_s0 = {0.f, 0.f, 0.f, 0.f}, acc_b0 = {0.f, 0.f, 0.f, 0.f};
  f32x4 acc_s1 = {0.f, 0.f, 0.f, 0.f}, acc_b1 = {0.f, 0.f, 0.f, 0.f};
  const f32x4 zero = {0.f, 0.f, 0.f, 0.f};
  const f16x8* a1 = (const f16x8*)a1pack;
  const f16x8* qp = (const f16x8*)qpack;

#define PK(dst, va, vb_) { auto _r = __builtin_amdgcn_cvt_pkrtz(va, vb_); dst = *(f16x2*)&_r; }
#define E(x) __builtin_amdgcn_exp2f(x)

#define DO_TILE(AS, AB, BS0, BB0, BS1, BB1)                                      \
  {                                                                              \
    f32x4 ax0 = __builtin_amdgcn_mfma_f32_16x16x32_f16(A, BS0, zero, 0, 0, 0);  \
    f32x4 ab0 = __builtin_amdgcn_mfma_f32_16x16x32_f16(A, BB0, zero, 0, 0, 0);  \
    f32x4 ax1 = __builtin_amdgcn_mfma_f32_16x16x32_f16(A, BS1, zero, 0, 0, 0);  \
    f32x4 ab1 = __builtin_amdgcn_mfma_f32_16x16x32_f16(A, BB1, zero, 0, 0, 0);  \
    F16x8U us, ub;                                                               \
    PK(us.h[0], E(ax0[0]), E(ax0[1]));                                           \
    PK(us.h[1], E(ax0[2]), E(ax0[3]));                                           \
    PK(us.h[2], E(ax1[0]), E(ax1[1]));                                           \
    PK(us.h[3], E(ax1[2]), E(ax1[3]));                                           \
    PK(ub.h[0], E(ab0[0]), E(ab0[1]));                                           \
    PK(ub.h[1], E(ab0[2]), E(ab0[3]));                                           \
    PK(ub.h[2], E(ab1[0]), E(ab1[1]));                                           \
    PK(ub.h[3], E(ab1[2]), E(ab1[3]));                                           \
    AS = __builtin_amdgcn_mfma_f32_16x16x32_f16(us.v, bq, AS, 0, 0, 0);          \
    AB = __builtin_amdgcn_mfma_f32_16x16x32_f16(ub.v, bq, AB, 0, 0, 0);          \
  }

  int sp0 = seg * NSP;
#pragma unroll 2
  for (int sp = sp0; sp < sp0 + NSP; ++sp) {
    f16x8 A  = a1[(size_t)sp * 64 + lane];
    f16x8 bq = qp[(size_t)sp * 64 + lane];
    DO_TILE(acc_s0, acc_b0, Bs0_0, Bb0_0, Bs1_0, Bb1_0)
    DO_TILE(acc_s1, acc_b1, Bs0_1, Bb0_1, Bs1_1, Bb1_1)
  }

  // D layout: col(lane&15) = label slot, row = 4*(lane>>4)+r = p offset
  size_t base0 = ((size_t)seg * N + ptile + g * 4) * 16 + rm;
  size_t base1 = ((size_t)seg * N + ptile + 16 + g * 4) * 16 + rm;
#pragma unroll
  for (int r = 0; r < 4; ++r) {
    ps[base0 + (size_t)r * 16] = acc_s0[r];
    pb[base0 + (size_t)r * 16] = acc_b0[r];
    ps[base1 + (size_t)r * 16] = acc_s1[r];
    pb[base1 + (size_t)r * 16] = acc_b1[r];
  }
}

// 256 blocks; tasks = (point within 32) x (src: S/B) x (col-quad).
// Folds BOTH 1/norm (col 13) and 1/D_l (softmax denominator, from part) into S/Bb.
__global__ __launch_bounds__(256) void reduce_kernel(const float* __restrict__ ps,
                                                     const float* __restrict__ pb,
                                                     const float* __restrict__ part,
                                                     float* __restrict__ S,
                                                     float* __restrict__ Bb) {
  int t = threadIdx.x;
  __shared__ float buf[13][256];
#pragma unroll
  for (int l = 0; l < L; ++l) {
    float v = part[t * 16 + l];
    if (t < PARTROWS - 256) v += part[(t + 256) * 16 + l];
    buf[l][t] = v;
  }
  __syncthreads();
  for (int s = 128; s >= 1; s >>= 1) {
    if (t < s) {
#pragma unroll
      for (int l = 0; l < L; ++l) buf[l][t] += buf[l][t + s];
    }
    __syncthreads();
  }

  int q = t & 3, src = (t >> 2) & 1, pi = t >> 3;
  int p = blockIdx.x * 32 + pi;
  const float* basep = src ? pb : ps;
  f32x4 acc = {0.f, 0.f, 0.f, 0.f};
#pragma unroll
  for (int seg = 0; seg < SEGS; ++seg)
    acc += *(const f32x4*)(basep + ((size_t)seg * N + p) * 16 + q * 4);

  __shared__ float nrm[64];
  if (q == 3) nrm[pi * 2 + src] = acc[1];  // col 13 = norm
  __syncthreads();
  float inv_norm = 1.0f / nrm[pi * 2 + src];
  float* dst = src ? Bb : S;
#pragma unroll
  for (int e = 0; e < 4; ++e) {
    int col = q * 4 + e;
    if (col < L) {
      float invD = 1.0f / ((float*)buf)[col * 256];  // buf[col][0]
      dst[(size_t)p * L + col] = acc[e] * invD * inv_norm;
    }
  }
}

// faithful reshape-mixing + next iteration's unnormalized softmax pack + label partial sums
__global__ __launch_bounds__(256) void mix_kernel(const float* __restrict__ S,
                                                  const float* __restrict__ Bb,
                                                  const float* __restrict__ M1,
                                                  const float* __restrict__ M2,
                                                  const float* __restrict__ logits,
                                                  float* __restrict__ cur,
                                                  unsigned short* __restrict__ qpack,
                                                  float* __restrict__ part) {
  int t = threadIdx.x;
  int i = blockIdx.x * 256 + t;           // grid is exactly N*L/256 = 416
  int c = i & (N - 1);
  int r = i >> 13;
  float v = 0.f;
#pragma unroll
  for (int j = 0; j < L; ++j) {
    v = fmaf(M1[r * L + j], S[(size_t)j * N + c], v);
    v = fmaf(M2[r * L + j], Bb[(size_t)j * N + c], v);
  }
  float o = v + logits[i];
  cur[i] = o;

  float e = __builtin_amdgcn_exp2f(o * C2 - EBIAS);
  unsigned int pr = (unsigned int)i / 13u;
  int l = i - pr * 13;
  int kc = pr >> 5, kk = pr & 31;
  int g = (kk < 16) ? (kk >> 2) : ((kk - 16) >> 2);
  int j2 = (kk < 16) ? (kk & 3) : (4 + (kk & 3));
  _Float16 h = (_Float16)e;
  qpack[((size_t)kc * 64 + g * 16 + l) * 8 + j2] = *(unsigned short*)&h;

  // deterministic per-block label sums: slot (l, t/13) is bijective in t
  __shared__ float buf[260];
  if (t < 260) buf[t] = 0.f;
  __syncthreads();
  buf[l * 20 + t / 13u] = e;
  __syncthreads();
  if (t < L) {
    float s_ = 0.f;
#pragma unroll
    for (int k = 0; k < 20; ++k) s_ += buf[t * 20 + k];
    part[blockIdx.x * 16 + t] = s_;
  }
}

extern "C" void kernel_launch(void* const* d_in, const int* in_sizes, int n_in,
                              void* d_out, int out_size, void* d_ws, size_t ws_size,
                              hipStream_t stream) {
  const float* points = (const float*)d_in[0];
  const float* logits = (const float*)d_in[1];
  const float* Ws = (const float*)d_in[2];
  const float* Wb = (const float*)d_in[3];
  const float* C = (const float*)d_in[4];

  float* cur = (float*)d_out;

  float* w = (float*)d_ws;
  float* crd  = w;                        w += 6 * N;
  float* snx  = w;                        w += N;
  float* snf  = w;                        w += N;
  float* ps   = w;                        w += (size_t)SEGS * N * 16;
  float* pb   = w;                        w += (size_t)SEGS * N * 16;
  float* S    = w;                        w += (size_t)L * N + 64;
  float* Bb   = w;                        w += (size_t)L * N + 64;
  float* M1   = w;                        w += 256;
  float* M2   = w;                        w += 256;
  float* part = w;                        w += PARTROWS * 16;
  unsigned short* a1pack = (unsigned short*)w;              // 256*64*8 u16 = 256 KB
  unsigned short* qpack  = a1pack + (size_t)256 * 64 * 8;   // 256 KB

  prep_kernel<<<N / 256, 256, 0, stream>>>(points, logits, crd, snx, snf, part, a1pack, qpack);
  mprep_kernel<<<1, 256, 0, stream>>>(Ws, Wb, C, M1, M2);

  for (int it = 0; it < 5; ++it) {
    filter_kernel<<<dim3(N / 128, SEGS), 256, 0, stream>>>(crd, snx, snf, a1pack, qpack, ps, pb);
    reduce_kernel<<<N / 32, 256, 0, stream>>>(ps, pb, part, S, Bb);
    mix_kernel<<<(N * L) / 256, 256, 0, stream>>>(S, Bb, M1, M2, logits, cur, qpack, part);
  }
}

// Round 7
// 187.317 us; speedup vs baseline: 1.0464x; 1.0464x over previous
//
#include <hip/hip_runtime.h>

#define N 8192
#define L 13
#define SEGS 8
#define NSP (N / SEGS / 32)  // 32 MFMA-group iterations per filter wave
#define PARTROWS 416         // = N*L/256 (mix grid); prep fills rows 0..31, zeros rest

typedef _Float16 f16x8 __attribute__((ext_vector_type(8)));
typedef _Float16 f16x2 __attribute__((ext_vector_type(2)));
typedef float f32x4 __attribute__((ext_vector_type(4)));
union F16x8U { f16x8 v; f16x2 h[4]; };

#define C1 (-0.72134752044448f)   // -0.5/ln2
#define C2 (1.44269504088896f)    // log2(e)
#define EBIAS 6.0f                // e' = exp2(C2*x - EBIAS); scale cancels in e'/D'

// a1pack [spair(256)][lane(64)][j(8)] f16 — A-frags (k-side quintuple/octuple).
// qpack  [kc(256)][lane=g*16+col][j(8)] f16 = e'[kc*32+phys(g,j)][col]; col13=1.0, col14/15=0.
//   phys(g,j) = j<4 ? 4g+j : 16+4g+(j-4)

__global__ __launch_bounds__(256) void prep_kernel(const float* __restrict__ points,
                                                   const float* __restrict__ logits,
                                                   float* __restrict__ crd,
                                                   float* __restrict__ snx,
                                                   float* __restrict__ snf,
                                                   float* __restrict__ part,
                                                   unsigned short* __restrict__ a1pack,
                                                   unsigned short* __restrict__ qpack) {
  int t = threadIdx.x;
  int p = blockIdx.x * 256 + t;
  float c6[6];
#pragma unroll
  for (int d = 0; d < 6; ++d) { c6[d] = points[p * 6 + d]; crd[d * N + p] = c6[d]; }
  float sx = c6[0] * c6[0] + c6[1] * c6[1] + c6[2] * c6[2];
  float sf = c6[3] * c6[3] + c6[4] * c6[4] + c6[5] * c6[5];
  snx[p] = sx; snf[p] = sf;

  int spair = p >> 5, w = p & 31, rm = w & 15;
  int laneS = (w < 16 ? 0 : 32) + rm;
  int laneB = (w < 16 ? 16 : 48) + rm;
  f16x8 vs = { (_Float16)c6[0], (_Float16)c6[1], (_Float16)c6[2],
               (_Float16)sx, (_Float16)1.0f, (_Float16)0.0f, (_Float16)0.0f, (_Float16)0.0f };
  f16x8 vb = { (_Float16)c6[0], (_Float16)c6[1], (_Float16)c6[2],
               (_Float16)c6[3], (_Float16)c6[4], (_Float16)c6[5],
               (_Float16)(sx + sf), (_Float16)1.0f };
  ((f16x8*)a1pack)[(size_t)spair * 64 + laneS] = vs;
  ((f16x8*)a1pack)[(size_t)spair * 64 + laneB] = vb;

  int kc = p >> 5, kk = p & 31;
  int g = (kk < 16) ? (kk >> 2) : ((kk - 16) >> 2);
  int j2 = (kk < 16) ? (kk & 3) : (4 + (kk & 3));
  size_t qb = ((size_t)kc * 64 + g * 16) * 8 + j2;
  qpack[qb + 13 * 8] = 0x3C00;  // f16 1.0 (norm column)
  qpack[qb + 14 * 8] = 0;
  qpack[qb + 15 * 8] = 0;

  // initial unnormalized-softmax pack + per-block label sums
  __shared__ float buf[13][256];
#pragma unroll
  for (int l = 0; l < L; ++l) {
    float e = __builtin_amdgcn_exp2f(logits[p * L + l] * C2 - EBIAS);
    _Float16 h = (_Float16)e;
    qpack[qb + (size_t)l * 8] = *(unsigned short*)&h;
    buf[l][t] = e;
  }
  __syncthreads();
  for (int s = 128; s >= 1; s >>= 1) {
    if (t < s) {
#pragma unroll
      for (int l = 0; l < L; ++l) buf[l][t] += buf[l][t + s];
    }
    __syncthreads();
  }
  if (t < L) part[blockIdx.x * 16 + t] = buf[t][0];
  if (t < 192) part[(32 + blockIdx.x * 12 + (t >> 4)) * 16 + (t & 15)] = 0.f;
}

__global__ void mprep_kernel(const float* __restrict__ Ws, const float* __restrict__ Wb,
                             const float* __restrict__ C, float* __restrict__ M1,
                             float* __restrict__ M2) {
  int i = threadIdx.x;
  if (i < L * L) {
    int r = i / L, c = i % L;
    float a = 0.f, b = 0.f;
    for (int j = 0; j < L; ++j) {
      a += C[r * L + j] * Ws[j * L + c];
      b += C[r * L + j] * Wb[j * L + c];
    }
    M1[i] = a; M2[i] = b;
  }
}

// hot kernel: 4 waves/block, 16 p-rows each, software-pipelined:
//   loads prefetched 2 iterations ahead; dot-MFMAs for sp+1 issued BEFORE the
//   exp block of sp (MFMA pipe overlaps trans pipe); acc-MFMA closes sp.
__global__ __launch_bounds__(256) void filter_kernel(const float* __restrict__ crd,
                                                     const float* __restrict__ snx,
                                                     const float* __restrict__ snf,
                                                     const unsigned short* __restrict__ a1pack,
                                                     const unsigned short* __restrict__ qpack,
                                                     float* __restrict__ ps,
                                                     float* __restrict__ pb) {
  int tid = threadIdx.x;
  int lane = tid & 63, wave = tid >> 6;
  int g = lane >> 4, rm = lane & 15;
  int ptile = blockIdx.x * 64 + wave * 16;
  int p = ptile + rm;
  int seg = blockIdx.y;

  float x0 = crd[p], x1 = crd[N + p], x2 = crd[2 * N + p];
  float f0 = crd[3 * N + p], f1 = crd[4 * N + p], f2 = crd[5 * N + p];
  float sx = snx[p], sf = snf[p];

  f16x8 spat = { (_Float16)(C2 * x0), (_Float16)(C2 * x1), (_Float16)(C2 * x2),
                 (_Float16)C1, (_Float16)(C1 * sx),
                 (_Float16)0.0f, (_Float16)0.0f, (_Float16)0.0f };
  f16x8 bil  = { (_Float16)(C2 * x0), (_Float16)(C2 * x1), (_Float16)(C2 * x2),
                 (_Float16)(C2 * f0), (_Float16)(C2 * f1), (_Float16)(C2 * f2),
                 (_Float16)C1, (_Float16)(C1 * (sx + sf)) };
  f16x8 z8 = {0, 0, 0, 0, 0, 0, 0, 0};
  f16x8 Bs0 = (g == 0) ? spat : z8;
  f16x8 Bb0 = (g == 1) ? bil : z8;
  f16x8 Bs1 = (g == 2) ? spat : z8;
  f16x8 Bb1 = (g == 3) ? bil : z8;

  f32x4 acc_s = {0.f, 0.f, 0.f, 0.f};
  f32x4 acc_b = {0.f, 0.f, 0.f, 0.f};
  const f32x4 zero = {0.f, 0.f, 0.f, 0.f};
  const f16x8* a1 = (const f16x8*)a1pack;
  const f16x8* qp = (const f16x8*)qpack;

#define PK(dst, va, vb_) { auto _r = __builtin_amdgcn_cvt_pkrtz(va, vb_); dst = *(f16x2*)&_r; }
#define E(x) __builtin_amdgcn_exp2f(x)
#define MFMA(a_, b_, c_) __builtin_amdgcn_mfma_f32_16x16x32_f16(a_, b_, c_, 0, 0, 0)

  int sp0 = seg * NSP;

  // prologue: prefetch sp0, sp0+1; dots for sp0
  f16x8 An, Qc, Qn;
  f32x4 ds0, db0, ds1, db1;
  {
    f16x8 A0 = a1[(size_t)sp0 * 64 + lane];
    Qc = qp[(size_t)sp0 * 64 + lane];
    An = a1[(size_t)(sp0 + 1) * 64 + lane];
    Qn = qp[(size_t)(sp0 + 1) * 64 + lane];
    ds0 = MFMA(A0, Bs0, zero);
    db0 = MFMA(A0, Bb0, zero);
    ds1 = MFMA(A0, Bs1, zero);
    db1 = MFMA(A0, Bb1, zero);
  }

#pragma unroll 2
  for (int sp = sp0; sp < sp0 + NSP; ++sp) {
    int spn = (sp + 2 <= 255) ? sp + 2 : 255;   // clamp: tail loads reuse last spair
    f16x8 Af = a1[(size_t)spn * 64 + lane];
    f16x8 Qf = qp[(size_t)spn * 64 + lane];

    // dot-MFMAs for sp+1 — independent of everything below, fills MFMA pipe
    f32x4 nds0 = MFMA(An, Bs0, zero);
    f32x4 ndb0 = MFMA(An, Bb0, zero);
    f32x4 nds1 = MFMA(An, Bs1, zero);
    f32x4 ndb1 = MFMA(An, Bb1, zero);

    // trans-pipe block on current dots (computed one iteration ago)
    F16x8U us, ub;
    PK(us.h[0], E(ds0[0]), E(ds0[1]));
    PK(us.h[1], E(ds0[2]), E(ds0[3]));
    PK(us.h[2], E(ds1[0]), E(ds1[1]));
    PK(us.h[3], E(ds1[2]), E(ds1[3]));
    PK(ub.h[0], E(db0[0]), E(db0[1]));
    PK(ub.h[1], E(db0[2]), E(db0[3]));
    PK(ub.h[2], E(db1[0]), E(db1[1]));
    PK(ub.h[3], E(db1[2]), E(db1[3]));

    acc_s = MFMA(us.v, Qc, acc_s);
    acc_b = MFMA(ub.v, Qc, acc_b);

    ds0 = nds0; db0 = ndb0; ds1 = nds1; db1 = ndb1;
    An = Af; Qc = Qn; Qn = Qf;
  }

  // D layout: col(lane&15) = label slot, row = 4*(lane>>4)+r = p offset
  int pout = ptile + g * 4;
  size_t base = ((size_t)seg * N + pout) * 16 + rm;
#pragma unroll
  for (int r = 0; r < 4; ++r) {
    ps[base + (size_t)r * 16] = acc_s[r];
    pb[base + (size_t)r * 16] = acc_b[r];
  }
}

// 256 blocks; tasks = (point within 32) x (src: S/B) x (col-quad).
// Folds BOTH 1/norm (col 13) and 1/D_l (softmax denominator, from part) into S/Bb.
__global__ __launch_bounds__(256) void reduce_kernel(const float* __restrict__ ps,
                                                     const float* __restrict__ pb,
                                                     const float* __restrict__ part,
                                                     float* __restrict__ S,
                                                     float* __restrict__ Bb) {
  int t = threadIdx.x;
  __shared__ float buf[13][256];
#pragma unroll
  for (int l = 0; l < L; ++l) {
    float v = part[t * 16 + l];
    if (t < PARTROWS - 256) v += part[(t + 256) * 16 + l];
    buf[l][t] = v;
  }
  __syncthreads();
  for (int s = 128; s >= 1; s >>= 1) {
    if (t < s) {
#pragma unroll
      for (int l = 0; l < L; ++l) buf[l][t] += buf[l][t + s];
    }
    __syncthreads();
  }

  int q = t & 3, src = (t >> 2) & 1, pi = t >> 3;
  int p = blockIdx.x * 32 + pi;
  const float* basep = src ? pb : ps;
  f32x4 acc = {0.f, 0.f, 0.f, 0.f};
#pragma unroll
  for (int seg = 0; seg < SEGS; ++seg)
    acc += *(const f32x4*)(basep + ((size_t)seg * N + p) * 16 + q * 4);

  __shared__ float nrm[64];
  if (q == 3) nrm[pi * 2 + src] = acc[1];  // col 13 = norm
  __syncthreads();
  float inv_norm = 1.0f / nrm[pi * 2 + src];
  float* dst = src ? Bb : S;
#pragma unroll
  for (int e = 0; e < 4; ++e) {
    int col = q * 4 + e;
    if (col < L) {
      float invD = 1.0f / ((float*)buf)[col * 256];  // buf[col][0]
      dst[(size_t)p * L + col] = acc[e] * invD * inv_norm;
    }
  }
}

// faithful reshape-mixing + next iteration's unnormalized softmax pack + label partial sums
__global__ __launch_bounds__(256) void mix_kernel(const float* __restrict__ S,
                                                  const float* __restrict__ Bb,
                                                  const float* __restrict__ M1,
                                                  const float* __restrict__ M2,
                                                  const float* __restrict__ logits,
                                                  float* __restrict__ cur,
                                                  unsigned short* __restrict__ qpack,
                                                  float* __restrict__ part) {
  int t = threadIdx.x;
  int i = blockIdx.x * 256 + t;           // grid is exactly N*L/256 = 416
  int c = i & (N - 1);
  int r = i >> 13;
  float v = 0.f;
#pragma unroll
  for (int j = 0; j < L; ++j) {
    v = fmaf(M1[r * L + j], S[(size_t)j * N + c], v);
    v = fmaf(M2[r * L + j], Bb[(size_t)j * N + c], v);
  }
  float o = v + logits[i];
  cur[i] = o;

  float e = __builtin_amdgcn_exp2f(o * C2 - EBIAS);
  unsigned int pr = (unsigned int)i / 13u;
  int l = i - pr * 13;
  int kc = pr >> 5, kk = pr & 31;
  int g = (kk < 16) ? (kk >> 2) : ((kk - 16) >> 2);
  int j2 = (kk < 16) ? (kk & 3) : (4 + (kk & 3));
  _Float16 h = (_Float16)e;
  qpack[((size_t)kc * 64 + g * 16 + l) * 8 + j2] = *(unsigned short*)&h;

  // deterministic per-block label sums: slot (l, t/13) is bijective in t
  __shared__ float buf[260];
  if (t < 260) buf[t] = 0.f;
  __syncthreads();
  buf[l * 20 + t / 13u] = e;
  __syncthreads();
  if (t < L) {
    float s_ = 0.f;
#pragma unroll
    for (int k = 0; k < 20; ++k) s_ += buf[t * 20 + k];
    part[blockIdx.x * 16 + t] = s_;
  }
}

extern "C" void kernel_launch(void* const* d_in, const int* in_sizes, int n_in,
                              void* d_out, int out_size, void* d_ws, size_t ws_size,
                              hipStream_t stream) {
  const float* points = (const float*)d_in[0];
  const float* logits = (const float*)d_in[1];
  const float* Ws = (const float*)d_in[2];
  const float* Wb = (const float*)d_in[3];
  const float* C = (const float*)d_in[4];

  float* cur = (float*)d_out;

  float* w = (float*)d_ws;
  float* crd  = w;                        w += 6 * N;
  float* snx  = w;                        w += N;
  float* snf  = w;                        w += N;
  float* ps   = w;                        w += (size_t)SEGS * N * 16;
  float* pb   = w;                        w += (size_t)SEGS * N * 16;
  float* S    = w;                        w += (size_t)L * N + 64;
  float* Bb   = w;                        w += (size_t)L * N + 64;
  float* M1   = w;                        w += 256;
  float* M2   = w;                        w += 256;
  float* part = w;                        w += PARTROWS * 16;
  unsigned short* a1pack = (unsigned short*)w;              // 256*64*8 u16 = 256 KB
  unsigned short* qpack  = a1pack + (size_t)256 * 64 * 8;   // 256 KB

  prep_kernel<<<N / 256, 256, 0, stream>>>(points, logits, crd, snx, snf, part, a1pack, qpack);
  mprep_kernel<<<1, 256, 0, stream>>>(Ws, Wb, C, M1, M2);

  for (int it = 0; it < 5; ++it) {
    filter_kernel<<<dim3(N / 64, SEGS), 256, 0, stream>>>(crd, snx, snf, a1pack, qpack, ps, pb);
    reduce_kernel<<<N / 32, 256, 0, stream>>>(ps, pb, part, S, Bb);
    mix_kernel<<<(N * L) / 256, 256, 0, stream>>>(S, Bb, M1, M2, logits, cur, qpack, part);
  }
}